// Round 2
// baseline (378.133 us; speedup 1.0000x reference)
//
#include <hip/hip_runtime.h>

// A=500 atoms, R=14 reps, n_ao=5800, out=[A,A,R,R]=49M f32 (196 MB).
// Scatter is collision-free: out[a1,a2,r1,r2] = feat[inv(a1,r1), inv(a2,r2)]
// or 0 at empty rep slots, where inv(a,r) = arow[a] + pm[a*R+r] (pm<0 = empty).
//
// v3 "direct gather": no LDS staging of feat at all. Per lane, the output
// positions e=4*lane..4*lane+3 have FIXED (r1,r2) -> fixed feat row base for
// the whole kernel. Per (a1,a2) tile a lane does: 4 small-LDS reads of a
// per-a2 column-offset table, 4 adds, 4 exec-masked global gathers, 1
// coalesced float4 store. Zero barriers in the hot loop; empties encoded as
// -2^30 sentinels so validity is a single (addr>=0) test.
// 2500 blocks x 256 thr, 5.6 KB LDS, ~35 VGPR -> 32 waves/CU for TLP.
constexpr int R = 14;
constexpr int A = 500;
constexpr int TOTAL = A * R;          // 7000
constexpr int TILE = R * R;           // 196
constexpr int APB = 100;              // a2 atoms per block
constexpr int BPA = A / APB;          // 5 blocks per a1
constexpr int TPW = APB / 4;          // 25 tiles per wave (4 waves/block)
constexpr int SENT = (int)0xC0000000; // -(1<<30) invalid sentinel

// ---- fused setup: one block (unchanged, known-good) ----------------------
__global__ __launch_bounds__(1024) void setup_kernel(
        const int* __restrict__ dst, int n_ao,
        int* __restrict__ inv, int* __restrict__ arow,
        int* __restrict__ ncols, int* __restrict__ pm) {
    int tid = threadIdx.x;
    for (int t = tid; t < TOTAL; t += 1024) inv[t] = -1;
    __syncthreads();
    for (int t = tid; t < n_ao; t += 1024) inv[dst[t]] = t;  // collision-free
    __syncthreads();
    if (tid < A) {
        int a = tid, lo = 0x7fffffff, hi = -1;
#pragma unroll
        for (int r = 0; r < R; ++r) {
            int v = inv[a * R + r];
            if (v >= 0) { lo = min(lo, v); hi = max(hi, v); }
        }
        arow[a] = lo;
        ncols[a] = hi - lo + 1;
#pragma unroll
        for (int r = 0; r < R; ++r) {
            int v = inv[a * R + r];
            pm[a * R + r] = (v >= 0) ? (v - lo) : -1;
        }
    }
}

// ---- main: 2500 blocks x 256 threads; block = (a1, 100 a2 atoms) ---------
__global__ __launch_bounds__(256, 8) void gather_kernel(
        const float* __restrict__ feat,
        const int* __restrict__ arow,
        const int* __restrict__ pm,
        float* __restrict__ out, int n_ao) {
    const int a1     = blockIdx.x / BPA;
    const int a2base = (blockIdx.x % BPA) * APB;
    const int tid    = threadIdx.x;
    const int wave   = tid >> 6;
    const int lane   = tid & 63;

    // per-a2 column offsets: s_cof[i*R + r2] = arow[a2]+pm[a2,r2] or SENT
    __shared__ int s_cof[APB * R];            // 5600 B
    for (int t = tid; t < APB * R; t += 256) {
        const int a2  = a2base + t / R;       // magic div
        const int pmv = pm[a2base * R + t];   // contiguous, coalesced
        s_cof[t] = (pmv >= 0) ? (arow[a2] + pmv) : SENT;
    }

    // ---- per-lane constants (fixed for the whole kernel) ----
    const bool active = (lane < 49);          // 196 floats / 4 per lane
    const int  e0     = active ? lane * 4 : 0;
    const int  arow1  = arow[a1];
    int rowb[4];                              // feat row base (elements) or SENT
    int r2o[4];                               // r2 index into s_cof row
#pragma unroll
    for (int k = 0; k < 4; ++k) {
        const int e  = e0 + k;
        const int r1 = e / R;
        r2o[k]       = e - r1 * R;
        const int dd = pm[a1 * R + r1];
        rowb[k] = (active && dd >= 0) ? (arow1 + dd) * n_ao : SENT;
    }
    __syncthreads();                          // the only barrier

    // ---- hot loop: 25 independent tiles per wave, no barriers ----
    const int  i0 = wave * TPW;               // chunked a2 range per wave
    float* const outw = out + ((long long)(a1 * A + a2base + i0)) * TILE
                            + (lane << 2);
#pragma unroll 2
    for (int i = 0; i < TPW; ++i) {
        const int* cof = &s_cof[(i0 + i) * R];
        float4 v = make_float4(0.f, 0.f, 0.f, 0.f);
        float* vp = &v.x;
#pragma unroll
        for (int k = 0; k < 4; ++k) {
            const int ad = rowb[k] + cof[r2o[k]];   // <0 iff any empty
            if (ad >= 0) vp[k] = feat[ad];          // exec-masked gather
        }
        if (active)
            *reinterpret_cast<float4*>(outw + (long long)i * TILE) = v;
    }
}

extern "C" void kernel_launch(void* const* d_in, const int* in_sizes, int n_in,
                              void* d_out, int out_size, void* d_ws, size_t ws_size,
                              hipStream_t stream) {
    const float* feat = (const float*)d_in[0];
    const int*   dst  = (const int*)d_in[1];
    int n_ao = in_sizes[1];              // 5800

    int* inv   = (int*)d_ws;             // 7000
    int* arow  = inv + TOTAL;            // 500
    int* ncols = arow + A;               // 500
    int* pm    = ncols + A;              // 7000

    setup_kernel<<<1, 1024, 0, stream>>>(dst, n_ao, inv, arow, ncols, pm);
    gather_kernel<<<A * BPA, 256, 0, stream>>>(feat, arow, pm,
                                               (float*)d_out, n_ao);
}